// Round 4
// baseline (547.874 us; speedup 1.0000x reference)
//
#include <hip/hip_runtime.h>
#include <math.h>

// Problem constants (B, L, D, H from the reference)
constexpr int Bsz = 4;
constexpr int Lsz = 2048;
constexpr int Dsz = 1024;
constexpr int Hn  = 8;
constexpr int Dh  = 128;   // Dsz / Hn
constexpr int GM  = Bsz * Lsz;   // 8192
constexpr int GK  = Dsz;         // 1024 (K dim of every projection GEMM)
constexpr int NT  = GK / 32;     // 32 K-tiles of BK=32

typedef __attribute__((ext_vector_type(8))) short bf16x8;
typedef __attribute__((ext_vector_type(4))) float f32x4;

union FragU { unsigned int u[4]; bf16x8 f; };

// async global->LDS, 16B per lane (wave-uniform base + lane*16 dest)
__device__ __forceinline__ void gload16(const void* g, void* l) {
    __builtin_amdgcn_global_load_lds(
        (const __attribute__((address_space(1))) unsigned int*)g,
        (__attribute__((address_space(3))) unsigned int*)l, 16, 0, 0);
}

// split two fp32 into packed bf16 hi-pair / lo-pair (hi=truncate, lo=residual)
__device__ __forceinline__ void split2(float f0, float f1,
                                       unsigned int& hp, unsigned int& lp) {
    unsigned int u0 = __float_as_uint(f0), u1 = __float_as_uint(f1);
    hp = (u0 >> 16) | (u1 & 0xffff0000u);
    float l0 = f0 - __uint_as_float(u0 & 0xffff0000u);
    float l1 = f1 - __uint_as_float(u1 & 0xffff0000u);
    lp = (__float_as_uint(l0) >> 16) | (__float_as_uint(l1) & 0xffff0000u);
}

// split 8 fp32 (two float4, k-contiguous) -> hi/lo A-fragments (in-register;
// identical math/packing to the original baseline's r2-proven frag build)
__device__ __forceinline__ void splitA(float4 f0, float4 f1, FragU& h, FragU& lo) {
    split2(f0.x, f0.y, h.u[0], lo.u[0]);
    split2(f0.z, f0.w, h.u[1], lo.u[1]);
    split2(f1.x, f1.y, h.u[2], lo.u[2]);
    split2(f1.z, f1.w, h.u[3], lo.u[3]);
}

__device__ __forceinline__ void split4(float4 f, ushort4& h, ushort4& l2) {
    unsigned int ux = __float_as_uint(f.x), uy = __float_as_uint(f.y),
                 uz = __float_as_uint(f.z), uw = __float_as_uint(f.w);
    h.x = (unsigned short)(ux >> 16); h.y = (unsigned short)(uy >> 16);
    h.z = (unsigned short)(uz >> 16); h.w = (unsigned short)(uw >> 16);
    float lx = f.x - __uint_as_float(ux & 0xffff0000u);
    float ly = f.y - __uint_as_float(uy & 0xffff0000u);
    float lz = f.z - __uint_as_float(uz & 0xffff0000u);
    float lw = f.w - __uint_as_float(uw & 0xffff0000u);
    l2.x = (unsigned short)(__float_as_uint(lx) >> 16);
    l2.y = (unsigned short)(__float_as_uint(ly) >> 16);
    l2.z = (unsigned short)(__float_as_uint(lz) >> 16);
    l2.w = (unsigned short)(__float_as_uint(lw) >> 16);
}

struct WConv4 {
    const float4* w[4];
    ushort4* h[4];
    ushort4* l[4];
    float s[4];
};

// 4 weights in one launch: 1024 blocks per weight (WD/4/256 = 1024)
__global__ __launch_bounds__(256) void conv_w4(WConv4 a) {
    int wi = blockIdx.x >> 10;
    int i = (blockIdx.x & 1023) * 256 + threadIdx.x;
    float4 f = a.w[wi][i];
    float s = a.s[wi];
    f.x *= s; f.y *= s; f.z *= s; f.w *= s;
    ushort4 h, l;
    split4(f, h, l);
    a.h[wi][i] = h; a.l[wi][i] = l;
}

// ---------------------------------------------------------------------------
// MFMA cluster: A-fragments come from REGISTERS (per-wave, loaded straight
// from global); only B is read from LDS (8 ds_read_b128 per wave per K-tile,
// down from 12 — the v3/v4 profile showed frag ds_reads exceeding MFMA work:
// 16 waves x 12 reads x ~12cy ~ 2300 cy/window/CU vs 1860 cy of MFMA).
// 3-product split-bf16 accumulation (hi*hi + hi*lo + lo*hi), order unchanged.
// ---------------------------------------------------------------------------
__device__ __forceinline__ void mfma_cluster(bf16x8 a0h, bf16x8 a0l,
                                             bf16x8 a1h, bf16x8 a1l,
                                             const ushort* Bh, const ushort* Bl,
                                             int wn, int l, f32x4 acc[2][4]) {
    bf16x8 bh[4], bl4[4];
#pragma unroll
    for (int fn = 0; fn < 4; ++fn) {
        int fng = wn * 4 + fn;
        bh[fn]  = *(const bf16x8*)&Bh[(fng * 64 + l) * 8];
        bl4[fn] = *(const bf16x8*)&Bl[(fng * 64 + l) * 8];
    }
    __builtin_amdgcn_s_setprio(1);
#pragma unroll
    for (int fn = 0; fn < 4; ++fn) {
        acc[0][fn] = __builtin_amdgcn_mfma_f32_16x16x32_bf16(a0h, bh[fn],  acc[0][fn], 0, 0, 0);
        acc[0][fn] = __builtin_amdgcn_mfma_f32_16x16x32_bf16(a0h, bl4[fn], acc[0][fn], 0, 0, 0);
        acc[0][fn] = __builtin_amdgcn_mfma_f32_16x16x32_bf16(a0l, bh[fn],  acc[0][fn], 0, 0, 0);
        acc[1][fn] = __builtin_amdgcn_mfma_f32_16x16x32_bf16(a1h, bh[fn],  acc[1][fn], 0, 0, 0);
        acc[1][fn] = __builtin_amdgcn_mfma_f32_16x16x32_bf16(a1h, bl4[fn], acc[1][fn], 0, 0, 0);
        acc[1][fn] = __builtin_amdgcn_mfma_f32_16x16x32_bf16(a1l, bh[fn],  acc[1][fn], 0, 0, 0);
    }
    __builtin_amdgcn_s_setprio(0);
}

// ---------------------------------------------------------------------------
// Fused QKV projection GEMM. N = 3072 over fused weights [Wq*s; Wk; Wv].
// v5: A-IN-REGISTERS. Each wave loads its OWN A-fragment rows directly from
// global (row = bm + wm*32 + fm*16 + (l&15), k = (l>>4)*8..+8): the lane-quad
// {l,l+16,l+32,l+48} shares a row and covers the full 128B line -> perfectly
// coalesced. A is split hi/lo in-register (r2-proven frag math). A never
// touches LDS: no A ds_write/ds_read, LDS halves to 32 KB (B hi/lo dbuf),
// LDS-read per window drops 12->8 ds_read_b128/wave. Waves sharing wm load A
// twice; second hit is L1-served. Sync = round-2's plain __syncthreads
// 2-phase (v4's counted-vmcnt asm regressed 135->141 us; reverted).
// B staging via global_load_lds, one tile ahead (proven path, unchanged).
// Outputs unchanged: cols [0,1024)->Qhi/Qlo; [1024,2048)->Khi/Klo row-major;
// [2048,3072)->Vthi/Vtlo TRANSPOSED. Row-tiles fully >= slen skip entirely.
// ---------------------------------------------------------------------------
__global__ __launch_bounds__(512, 4) void gemm_qkv(
    const float* __restrict__ Aq, const float* __restrict__ Ak,
    const ushort* __restrict__ Wfh, const ushort* __restrict__ Wfl,
    ushort* __restrict__ Qhi, ushort* __restrict__ Qlo,
    ushort* __restrict__ Khi, ushort* __restrict__ Klo,
    ushort* __restrict__ Vthi, ushort* __restrict__ Vtlo,
    const int* __restrict__ slen)
{
    const int tid = threadIdx.x;
    const int bm = blockIdx.y << 7;
    const int bn = blockIdx.x << 7;        // 0..2944 (fused N = 3072)
    const int grp = bn >> 10;              // 0:Q 1:K 2:V

    const int nk = slen[bm >> 11];
    if ((bm & (Lsz - 1)) >= nk) return;    // skipped tile, never read downstream

    // B double-buffer only: [buf][hi/lo][128*32] = 32 KB
    __shared__ __align__(16) ushort Bs[2][2][128 * 32];

    const float* A = (grp == 0) ? Aq : Ak;
    const int w  = tid >> 6;
    const int l  = tid & 63;
    const int wm = w >> 1;                 // 0..3 (M)
    const int wn = w & 1;                  // 0..1 (N)
    const int lg = l >> 4, lc = l & 15;

    // per-wave A fragment row pointers (fm = 0, 1)
    const float* agA0 = A + (size_t)(bm + wm * 32 +  0 + lc) * GK + lg * 8;
    const float* agA1 = A + (size_t)(bm + wm * 32 + 16 + lc) * GK + lg * 8;

    // B staging: 512 threads x one 16B chunk each of hi and lo per K-tile
    const int brow = ((tid >> 6) << 4) + (tid & 15);
    const int bkk  = ((tid >> 4) & 3) << 3;
    const ushort* bgh = Wfh + (size_t)(bn + brow) * GK + bkk;
    const ushort* bgl = Wfl + (size_t)(bn + brow) * GK + bkk;

    f32x4 acc[2][4];
#pragma unroll
    for (int i = 0; i < 2; ++i)
#pragma unroll
        for (int j = 0; j < 4; ++j) acc[i][j] = (f32x4)0.f;

    // ---- prologue: A(0)->c regs, B(0)->buf0, A(1)->n regs -----------------
    float4 c00 = *(const float4*)(agA0);
    float4 c01 = *(const float4*)(agA0 + 4);
    float4 c10 = *(const float4*)(agA1);
    float4 c11 = *(const float4*)(agA1 + 4);
    gload16(bgh, &Bs[0][0][tid * 8]);
    gload16(bgl, &Bs[0][1][tid * 8]);
    float4 n00 = *(const float4*)(agA0 + 32);
    float4 n01 = *(const float4*)(agA0 + 36);
    float4 n10 = *(const float4*)(agA1 + 32);
    float4 n11 = *(const float4*)(agA1 + 36);
    __syncthreads();

    // ---- windows 0..29, 2x unrolled (c/n register sets alternate) ---------
    for (int t = 0; t < NT - 2; t += 2) {
        // even window t: stage B(t+1)->buf1, compute tile t (c regs, buf0)
        gload16(bgh + (t + 1) * 32, &Bs[1][0][tid * 8]);
        gload16(bgl + (t + 1) * 32, &Bs[1][1][tid * 8]);
        {
            FragU a0h, a0l, a1h, a1l;
            splitA(c00, c01, a0h, a0l);
            splitA(c10, c11, a1h, a1l);
            c00 = *(const float4*)(agA0 + (t + 2) * 32);     // prefetch A(t+2)
            c01 = *(const float4*)(agA0 + (t + 2) * 32 + 4);
            c10 = *(const float4*)(agA1 + (t + 2) * 32);
            c11 = *(const float4*)(agA1 + (t + 2) * 32 + 4);
            mfma_cluster(a0h.f, a0l.f, a1h.f, a1l.f,
                         &Bs[0][0][0], &Bs[0][1][0], wn, l, acc);
        }
        __syncthreads();

        // odd window t+1: stage B(t+2)->buf0, compute tile t+1 (n regs, buf1)
        gload16(bgh + (t + 2) * 32, &Bs[0][0][tid * 8]);
        gload16(bgl + (t + 2) * 32, &Bs[0][1][tid * 8]);
        {
            FragU a0h, a0l, a1h, a1l;
            splitA(n00, n01, a0h, a0l);
            splitA(n10, n11, a1h, a1l);
            n00 = *(const float4*)(agA0 + (t + 3) * 32);     // prefetch A(t+3)<=31
            n01 = *(const float4*)(agA0 + (t + 3) * 32 + 4);
            n10 = *(const float4*)(agA1 + (t + 3) * 32);
            n11 = *(const float4*)(agA1 + (t + 3) * 32 + 4);
            mfma_cluster(a0h.f, a0l.f, a1h.f, a1l.f,
                         &Bs[1][0][0], &Bs[1][1][0], wn, l, acc);
        }
        __syncthreads();
    }

    // ---- window 30: stage B(31)->buf1, compute tile 30 (c regs, buf0) -----
    gload16(bgh + (NT - 1) * 32, &Bs[1][0][tid * 8]);
    gload16(bgl + (NT - 1) * 32, &Bs[1][1][tid * 8]);
    {
        FragU a0h, a0l, a1h, a1l;
        splitA(c00, c01, a0h, a0l);
        splitA(c10, c11, a1h, a1l);
        mfma_cluster(a0h.f, a0l.f, a1h.f, a1l.f,
                     &Bs[0][0][0], &Bs[0][1][0], wn, l, acc);
    }
    __syncthreads();

    // ---- window 31: compute tile 31 (n regs, buf1) ------------------------
    {
        FragU a0h, a0l, a1h, a1l;
        splitA(n00, n01, a0h, a0l);
        splitA(n10, n11, a1h, a1l);
        mfma_cluster(a0h.f, a0l.f, a1h.f, a1l.f,
                     &Bs[1][0][0], &Bs[1][1][0], wn, l, acc);
    }

    // epilogue: C/D layout row=(l>>4)*4+reg, col=l&15 (m89-verified)
    const int rq = (l >> 4) << 2;
    const int cq = l & 15;
    ushort* OH = (grp == 0) ? Qhi : Khi;   // grp 2 handled below
    ushort* OL = (grp == 0) ? Qlo : Klo;
#pragma unroll
    for (int fm = 0; fm < 2; ++fm) {
        int r0 = bm + wm * 32 + fm * 16 + rq;
#pragma unroll
        for (int fn = 0; fn < 4; ++fn) {
            int cn = (bn & 1023) + wn * 64 + fn * 16 + cq;
            if (grp < 2) {   // Q or K: row-major hi/lo
#pragma unroll
                for (int r = 0; r < 4; ++r) {
                    float f = acc[fm][fn][r];
                    unsigned int u = __float_as_uint(f);
                    float res = f - __uint_as_float(u & 0xffff0000u);
                    OH[(size_t)(r0 + r) * Dsz + cn] = (unsigned short)(u >> 16);
                    OL[(size_t)(r0 + r) * Dsz + cn] =
                        (unsigned short)(__float_as_uint(res) >> 16);
                }
            } else {         // V: transposed hi/lo
                ushort4 h4, l4;
                unsigned short* hp = (unsigned short*)&h4;
                unsigned short* lp = (unsigned short*)&l4;
#pragma unroll
                for (int r = 0; r < 4; ++r) {
                    float f = acc[fm][fn][r];
                    unsigned int u = __float_as_uint(f);
                    float res = f - __uint_as_float(u & 0xffff0000u);
                    hp[r] = (unsigned short)(u >> 16);
                    lp[r] = (unsigned short)(__float_as_uint(res) >> 16);
                }
                *(ushort4*)&Vthi[(size_t)cn * GM + r0] = h4;
                *(ushort4*)&Vtlo[(size_t)cn * GM + r0] = l4;
            }
        }
    }
}

// ---------------------------------------------------------------------------
// O-projection GEMM: out = O @ Wo^T, fp32 result. A pre-split (flash epilogue).
// v5: A-in-registers (already bf16 hi/lo in memory -> plain bf16x8 frag
// loads, no split at all). Lane-quad {l,l+16,l+32,l+48} reads 4x16B
// consecutive within the row -> fully coalesced. LDS = B hi/lo dbuf (32 KB).
// Plain __syncthreads 2-phase. Skipped row-tiles write zeros.
// ---------------------------------------------------------------------------
__global__ __launch_bounds__(512, 4) void gemm_o(
    const ushort* __restrict__ Ahi, const ushort* __restrict__ Alo,
    const ushort* __restrict__ Bhi, const ushort* __restrict__ Blo,
    float* __restrict__ C, const int* __restrict__ slen)
{
    const int tid = threadIdx.x;
    const int bm = blockIdx.y << 7;
    const int bn = blockIdx.x << 7;

    const int nk = slen[bm >> 11];
    if ((bm & (Lsz - 1)) >= nk) {
        int row = tid >> 2;
        int cb  = (tid & 3) << 5;          // 4 col-chunks of 32 floats
        float4 z = make_float4(0.f, 0.f, 0.f, 0.f);
        float4* cp = (float4*)(C + (size_t)(bm + row) * Dsz + bn + cb);
#pragma unroll
        for (int i = 0; i < 8; ++i) cp[i] = z;
        return;
    }

    __shared__ __align__(16) ushort Bs[2][2][128 * 32];

    const int w  = tid >> 6;
    const int l  = tid & 63;
    const int wm = w >> 1;
    const int wn = w & 1;
    const int lg = l >> 4, lc = l & 15;

    // per-wave A fragment row pointers (fm = 0, 1), hi and lo planes
    const ushort* a0hP = Ahi + (size_t)(bm + wm * 32 +  0 + lc) * GK + lg * 8;
    const ushort* a0lP = Alo + (size_t)(bm + wm * 32 +  0 + lc) * GK + lg * 8;
    const ushort* a1hP = Ahi + (size_t)(bm + wm * 32 + 16 + lc) * GK + lg * 8;
    const ushort* a1lP = Alo + (size_t)(bm + wm * 32 + 16 + lc) * GK + lg * 8;

    const int srow = ((tid >> 6) << 4) + (tid & 15);
    const int skk  = ((tid >> 4) & 3) << 3;
    const ushort* bgh = Bhi + (size_t)(bn + srow) * GK + skk;
    const ushort* bgl = Blo + (size_t)(bn + srow) * GK + skk;

    f32x4 acc[2][4];
#pragma unroll
    for (int i = 0; i < 2; ++i)
#pragma unroll
        for (int j = 0; j < 4; ++j) acc[i][j] = (f32x4)0.f;

    // ---- prologue: A(0)->c regs, B(0)->buf0, A(1)->n regs -----------------
    bf16x8 c0h = *(const bf16x8*)(a0hP), c0l = *(const bf16x8*)(a0lP);
    bf16x8 c1h = *(const bf16x8*)(a1hP), c1l = *(const bf16x8*)(a1lP);
    gload16(bgh, &Bs[0][0][tid * 8]);
    gload16(bgl, &Bs[0][1][tid * 8]);
    bf16x8 n0h = *(const bf16x8*)(a0hP + 32), n0l = *(const bf16x8*)(a0lP + 32);
    bf16x8 n1h = *(const bf16x8*)(a1hP + 32), n1l = *(const bf16x8*)(a1lP + 32);
    __syncthreads();

    for (int t = 0; t < NT - 2; t += 2) {
        // even window t: stage B(t+1)->buf1, compute tile t (c regs, buf0)
        gload16(bgh + (t + 1) * 32, &Bs[1][0][tid * 8]);
        gload16(bgl + (t + 1) * 32, &Bs[1][1][tid * 8]);
        {
            bf16x8 a0h = c0h, a0l = c0l, a1h = c1h, a1l = c1l;
            c0h = *(const bf16x8*)(a0hP + (t + 2) * 32);
            c0l = *(const bf16x8*)(a0lP + (t + 2) * 32);
            c1h = *(const bf16x8*)(a1hP + (t + 2) * 32);
            c1l = *(const bf16x8*)(a1lP + (t + 2) * 32);
            mfma_cluster(a0h, a0l, a1h, a1l,
                         &Bs[0][0][0], &Bs[0][1][0], wn, l, acc);
        }
        __syncthreads();

        // odd window t+1: stage B(t+2)->buf0, compute tile t+1 (n regs, buf1)
        gload16(bgh + (t + 2) * 32, &Bs[0][0][tid * 8]);
        gload16(bgl + (t + 2) * 32, &Bs[0][1][tid * 8]);
        {
            bf16x8 a0h = n0h, a0l = n0l, a1h = n1h, a1l = n1l;
            n0h = *(const bf16x8*)(a0hP + (t + 3) * 32);
            n0l = *(const bf16x8*)(a0lP + (t + 3) * 32);
            n1h = *(const bf16x8*)(a1hP + (t + 3) * 32);
            n1l = *(const bf16x8*)(a1lP + (t + 3) * 32);
            mfma_cluster(a0h, a0l, a1h, a1l,
                         &Bs[1][0][0], &Bs[1][1][0], wn, l, acc);
        }
        __syncthreads();
    }
    // window 30: stage B(31)->buf1, compute tile 30 (c regs, buf0)
    gload16(bgh + (NT - 1) * 32, &Bs[1][0][tid * 8]);
    gload16(bgl + (NT - 1) * 32, &Bs[1][1][tid * 8]);
    mfma_cluster(c0h, c0l, c1h, c1l, &Bs[0][0][0], &Bs[0][1][0], wn, l, acc);
    __syncthreads();
    // window 31: compute tile 31 (n regs, buf1)
    mfma_cluster(n0h, n0l, n1h, n1l, &Bs[1][0][0], &Bs[1][1][0], wn, l, acc);

    const int rq = (l >> 4) << 2;
    const int cq = l & 15;
#pragma unroll
    for (int fm = 0; fm < 2; ++fm) {
        int r0 = bm + wm * 32 + fm * 16 + rq;
#pragma unroll
        for (int fn = 0; fn < 4; ++fn) {
            int c0 = bn + wn * 64 + fn * 16 + cq;
#pragma unroll
            for (int r = 0; r < 4; ++r)
                C[(size_t)(r0 + r) * Dsz + c0] = acc[fm][fn][r];
        }
    }
}

// ---------------------------------------------------------------------------
// MFMA flash attention, split-bf16, max-free online softmax.
// BQ=128 (512 threads = 8 waves, 16 q-rows each), BK=32, SINGLE-buffered
// (dbuf regressed earlier: LDS 73 KB cut occupancy 3->2 blocks/CU).
// Masked q-tiles return immediately (gemm_o zero-fills them).
// O written pre-split in-place over Qhi/Qlo (block reads exactly the
// 128-aligned region it writes).  [unchanged from the 395us round-2 kernel]
// ---------------------------------------------------------------------------
__global__ __launch_bounds__(512) void flash_mfma(
    const ushort* __restrict__ Qhi, const ushort* __restrict__ Qlo,
    const ushort* __restrict__ Khi, const ushort* __restrict__ Klo,
    const ushort* __restrict__ Vthi, const ushort* __restrict__ Vtlo,
    const int* __restrict__ slen,
    ushort* __restrict__ Ohi, ushort* __restrict__ Olo)
{
    __shared__ __align__(16) ushort Ks[32 * 256];           // 16 KB
    __shared__ __align__(16) ushort Vs[128 * 64];           // 16 KB
    __shared__ __align__(16) unsigned int Pb[8 * 16 * 36];  // 18 KB

    const int tid = threadIdx.x;
    const int w = tid >> 6, l = tid & 63;
    const int lg = l >> 4, lc = l & 15;
    const int q0 = blockIdx.x << 7;        // 128-row q-tile
    const int h = blockIdx.y, b = blockIdx.z;
    const int nk = slen[b];

    if (q0 >= nk) return;   // gemm_o zero-fills these 128-aligned tiles

    // ---- Q strip -> A-frags (pre-split bf16), once per block ----
    bf16x8 qh[4], ql[4];
    {
        size_t base = (size_t)(b * Lsz + q0 + (w << 4) + lc) * Dsz + h * Dh + lg * 8;
#pragma unroll
        for (int s = 0; s < 4; ++s) {
            qh[s] = *(const bf16x8*)&Qhi[base + s * 32];
            ql[s] = *(const bf16x8*)&Qlo[base + s * 32];
        }
    }

    // ---- staging decode (512 threads, 1024 chunks each of K and Vt) ----
    const ushort* ksrc[2]; int klds[2];
    const ushort* vsrc[2]; int vlds[2];
#pragma unroll
    for (int i = 0; i < 2; ++i) {
        int s = i * 512 + tid;              // K chunk: row j (32ch: 16 hi + 16 lo)
        int j = s >> 5, p = s & 31;
        int lg4 = (p & 15) ^ (j & 15);
        const ushort* base = (p & 16) ? Klo : Khi;
        ksrc[i] = base + (size_t)(b * Lsz + j) * Dsz + h * Dh + lg4 * 8;
        klds[i] = s * 8;
    }
#pragma unroll
    for (int i = 0; i < 2; ++i) {
        int s = i * 512 + tid;              // Vt chunk: row d (8ch: 4 hi + 4 lo)
        int d = s >> 3, p = s & 7;
        int lgc = p ^ (d & 7);
        const ushort* base = (lgc & 4) ? Vtlo : Vthi;
        vsrc[i] = base + (size_t)(h * Dh + d) * (Bsz * Lsz) + b * Lsz + (lgc & 3) * 8;
        vlds[i] = s * 8;
    }

    f32x4 oacc[8];
#pragma unroll
    for (int fd = 0; fd < 8; ++fd) oacc[fd] = (f32x4)0.f;
    float lsum[4] = {0.f, 0.f, 0.f, 0.f};
    const int pbase = w * (16 * 36);

    for (int kb = 0; kb < nk; kb += 32) {
        // ---- stage K + V^T tiles ----
#pragma unroll
        for (int i = 0; i < 2; ++i) gload16(ksrc[i] + (size_t)kb * Dsz, &Ks[klds[i]]);
#pragma unroll
        for (int i = 0; i < 2; ++i) gload16(vsrc[i] + kb, &Vs[vlds[i]]);
        __syncthreads();

        // ---- S = Q K^T (16x32 per wave) ----
        f32x4 sa[2] = {(f32x4)0.f, (f32x4)0.f};
#pragma unroll
        for (int fn = 0; fn < 2; ++fn) {
            int j = fn * 16 + lc;
            int ro = j * 256;
#pragma unroll
            for (int s = 0; s < 4; ++s) {
                int phys = (s * 4 + lg) ^ (j & 15);
                bf16x8 kh = *(const bf16x8*)&Ks[ro + phys * 8];
                bf16x8 kl = *(const bf16x8*)&Ks[ro + 128 + phys * 8];
                sa[fn] = __builtin_amdgcn_mfma_f32_16x16x32_bf16(qh[s], kh, sa[fn], 0, 0, 0);
                sa[fn] = __builtin_amdgcn_mfma_f32_16x16x32_bf16(qh[s], kl, sa[fn], 0, 0, 0);
                sa[fn] = __builtin_amdgcn_mfma_f32_16x16x32_bf16(ql[s], kh, sa[fn], 0, 0, 0);
            }
        }

        // ---- mask tail keys (last tile only; wave-uniform branch) ----
        if (kb + 32 > nk) {
#pragma unroll
            for (int fn = 0; fn < 2; ++fn) {
                bool oob = (kb + fn * 16 + lc) >= nk;
#pragma unroll
                for (int rr = 0; rr < 4; ++rr)
                    sa[fn][rr] = oob ? -1e30f : sa[fn][rr];
            }
        }

        // ---- exp (max-free), accumulate row sums, split+pack P to LDS ----
#pragma unroll
        for (int fn = 0; fn < 2; ++fn)
#pragma unroll
            for (int rr = 0; rr < 4; ++rr) {
                float p = __expf(sa[fn][rr]);
                lsum[rr] += p;
                unsigned int u = __float_as_uint(p);
                float res = p - __uint_as_float(u & 0xffff0000u);
                unsigned int lo16 = __float_as_uint(res) >> 16;
                Pb[pbase + (lg * 4 + rr) * 36 + fn * 16 + lc] =
                    (lo16 << 16) | (u >> 16);
            }

        // ---- P: LDS -> A-frags (per-wave region; no barrier needed) ----
        const unsigned int* pr = &Pb[pbase + lc * 36 + lg * 8];
        uint4 a0 = *(const uint4*)pr;
        uint4 a1 = *(const uint4*)(pr + 4);
        FragU PH, PL;
        PH.u[0] = (a0.x & 0xffffu) | (a0.y << 16);
        PH.u[1] = (a0.z & 0xffffu) | (a0.w << 16);
        PH.u[2] = (a1.x & 0xffffu) | (a1.y << 16);
        PH.u[3] = (a1.z & 0xffffu) | (a1.w << 16);
        PL.u[0] = (a0.x >> 16) | (a0.y & 0xffff0000u);
        PL.u[1] = (a0.z >> 16) | (a0.w & 0xffff0000u);
        PL.u[2] = (a1.x >> 16) | (a1.y & 0xffff0000u);
        PL.u[3] = (a1.z >> 16) | (a1.w & 0xffff0000u);

        // ---- O += P V (16x128 per wave) ----
#pragma unroll
        for (int fd = 0; fd < 8; ++fd) {
            int d = fd * 16 + lc;
            int ro = d * 64;
            int ph = lg ^ (d & 7);
            int pl2 = (4 + lg) ^ (d & 7);
            bf16x8 vh = *(const bf16x8*)&Vs[ro + ph * 8];
            bf16x8 vl = *(const bf16x8*)&Vs[ro + pl2 * 8];
            oacc[fd] = __builtin_amdgcn_mfma_f32_16x16x32_bf16(PH.f, vh, oacc[fd], 0, 0, 0);
            oacc[fd] = __builtin_amdgcn_mfma_f32_16x16x32_bf16(PH.f, vl, oacc[fd], 0, 0, 0);
            oacc[fd] = __builtin_amdgcn_mfma_f32_16x16x32_bf16(PL.f, vh, oacc[fd], 0, 0, 0);
        }
        __syncthreads();   // protect Ks/Vs before next stage
    }

    // ---- reduce row sums across the 16 lanes of each quad group ----
#pragma unroll
    for (int m = 1; m < 16; m <<= 1)
#pragma unroll
        for (int rr = 0; rr < 4; ++rr)
            lsum[rr] += __shfl_xor(lsum[rr], m, 64);

    // ---- normalize, query-mask, split, store (in-place over Qhi/Qlo) ----
#pragma unroll
    for (int rr = 0; rr < 4; ++rr) {
        int q = q0 + (w << 4) + (lg << 2) + rr;
        bool valid = q < nk;
        float inv = valid ? (1.f / lsum[rr]) : 0.f;
        size_t base = (size_t)(b * Lsz + q) * Dsz + h * Dh + lc;
#pragma unroll
        for (int fd = 0; fd < 8; ++fd) {
            float val = valid ? oacc[fd][rr] * inv : 0.f;
            unsigned int u = __float_as_uint(val);
            float res = val - __uint_as_float(u & 0xffff0000u);
            Ohi[base + fd * 16] = (unsigned short)(u >> 16);
            Olo[base + fd * 16] = (unsigned short)(__float_as_uint(res) >> 16);
        }
    }
}

// ---------------------------------------------------------------------------
// ws: Qhi|Qlo|Khi|Klo|Vthi|Vtlo (6 x MD ushort) + Wfh|Wfl (fused QKV weights,
// 2 x 3WD) + Woh|Wol (2 x WD) = 6 MD + 8 WD ushort = 117.4 MB (validated).
// 4 launches total: conv_w4, gemm_qkv, flash_mfma, gemm_o.
// ---------------------------------------------------------------------------
extern "C" void kernel_launch(void* const* d_in, const int* in_sizes, int n_in,
                              void* d_out, int out_size, void* d_ws, size_t ws_size,
                              hipStream_t stream) {
    (void)in_sizes; (void)n_in; (void)out_size; (void)ws_size;
    const float* queries = (const float*)d_in[0];
    const float* keys    = (const float*)d_in[1];
    const int*   slen    = (const int*)d_in[2];
    const float* Wq      = (const float*)d_in[3];
    const float* Wk      = (const float*)d_in[4];
    const float* Wv      = (const float*)d_in[5];
    const float* Wo      = (const float*)d_in[6];
    float* out = (float*)d_out;

    const size_t MD = (size_t)Bsz * Lsz * Dsz;   // 8388608
    const size_t WD = (size_t)Dsz * Dsz;         // 1048576
    ushort* Qhi  = (ushort*)d_ws;
    ushort* Qlo  = Qhi + MD;
    ushort* Khi  = Qlo + MD;
    ushort* Klo  = Khi + MD;
    ushort* Vthi = Klo + MD;
    ushort* Vtlo = Vthi + MD;
    ushort* Wfh  = Vtlo + MD;      // fused: rows [0,1024)=Wq*s, [1024,2048)=Wk, [2048,3072)=Wv
    ushort* Wfl  = Wfh + 3 * WD;
    ushort* Woh  = Wfl + 3 * WD;
    ushort* Wol  = Woh + WD;

    const float scaleQ = 0.08838834764831845f;   // 1/sqrt(Dh), folded into Wq
    WConv4 wa;
    wa.w[0] = (const float4*)Wq; wa.h[0] = (ushort4*)Wfh;            wa.l[0] = (ushort4*)Wfl;            wa.s[0] = scaleQ;
    wa.w[1] = (const float4*)Wk; wa.h[1] = (ushort4*)(Wfh + WD);     wa.l[1] = (ushort4*)(Wfl + WD);     wa.s[1] = 1.f;
    wa.w[2] = (const float4*)Wv; wa.h[2] = (ushort4*)(Wfh + 2 * WD); wa.l[2] = (ushort4*)(Wfl + 2 * WD); wa.s[2] = 1.f;
    wa.w[3] = (const float4*)Wo; wa.h[3] = (ushort4*)Woh;            wa.l[3] = (ushort4*)Wol;            wa.s[3] = 1.f;
    conv_w4<<<4096, 256, 0, stream>>>(wa);

    // fused Q+K+V projections: N = 3072, grid (24, 64), 512 threads
    gemm_qkv<<<dim3(24, 64), 512, 0, stream>>>(
        queries, keys, Wfh, Wfl, Qhi, Qlo, Khi, Klo, Vthi, Vtlo, slen);

    // flash attention: 128-row q-tiles, 512 threads
    dim3 ga(Lsz / 128, Hn, Bsz);       // (16, 8, 4)
    flash_mfma<<<ga, 512, 0, stream>>>(Qhi, Qlo, Khi, Klo, Vthi, Vtlo, slen,
                                       Qhi, Qlo /* O in-place */);

    // output projection (reads pre-split O; masked tiles -> zeros)
    gemm_o<<<dim3(8, 64), 512, 0, stream>>>(Qhi, Qlo, Woh, Wol, out, slen);
}

// Round 5
// 442.479 us; speedup vs baseline: 1.2382x; 1.2382x over previous
//
#include <hip/hip_runtime.h>
#include <math.h>

// Problem constants (B, L, D, H from the reference)
constexpr int Bsz = 4;
constexpr int Lsz = 2048;
constexpr int Dsz = 1024;
constexpr int Hn  = 8;
constexpr int Dh  = 128;   // Dsz / Hn
constexpr int GM  = Bsz * Lsz;   // 8192
constexpr int GK  = Dsz;         // 1024 (K dim of every projection GEMM)
constexpr int NT  = GK / 32;     // 32 K-tiles of BK=32

typedef __attribute__((ext_vector_type(8))) short bf16x8;
typedef __attribute__((ext_vector_type(4))) float f32x4;

union FragU { unsigned int u[4]; bf16x8 f; };

// async global->LDS, 16B per lane (wave-uniform base + lane*16 dest)
__device__ __forceinline__ void gload16(const void* g, void* l) {
    __builtin_amdgcn_global_load_lds(
        (const __attribute__((address_space(1))) unsigned int*)g,
        (__attribute__((address_space(3))) unsigned int*)l, 16, 0, 0);
}

// split two fp32 into packed bf16 hi-pair / lo-pair (hi=truncate, lo=residual)
__device__ __forceinline__ void split2(float f0, float f1,
                                       unsigned int& hp, unsigned int& lp) {
    unsigned int u0 = __float_as_uint(f0), u1 = __float_as_uint(f1);
    hp = (u0 >> 16) | (u1 & 0xffff0000u);
    float l0 = f0 - __uint_as_float(u0 & 0xffff0000u);
    float l1 = f1 - __uint_as_float(u1 & 0xffff0000u);
    lp = (__float_as_uint(l0) >> 16) | (__float_as_uint(l1) & 0xffff0000u);
}

__device__ __forceinline__ void split4(float4 f, ushort4& h, ushort4& l2) {
    unsigned int ux = __float_as_uint(f.x), uy = __float_as_uint(f.y),
                 uz = __float_as_uint(f.z), uw = __float_as_uint(f.w);
    h.x = (unsigned short)(ux >> 16); h.y = (unsigned short)(uy >> 16);
    h.z = (unsigned short)(uz >> 16); h.w = (unsigned short)(uw >> 16);
    float lx = f.x - __uint_as_float(ux & 0xffff0000u);
    float ly = f.y - __uint_as_float(uy & 0xffff0000u);
    float lz = f.z - __uint_as_float(uz & 0xffff0000u);
    float lw = f.w - __uint_as_float(uw & 0xffff0000u);
    l2.x = (unsigned short)(__float_as_uint(lx) >> 16);
    l2.y = (unsigned short)(__float_as_uint(ly) >> 16);
    l2.z = (unsigned short)(__float_as_uint(lz) >> 16);
    l2.w = (unsigned short)(__float_as_uint(lw) >> 16);
}

struct WConv4 {
    const float4* w[4];
    ushort4* h[4];
    ushort4* l[4];
    float s[4];
};

// 4 weights in one launch: 1024 blocks per weight (WD/4/256 = 1024)
__global__ __launch_bounds__(256) void conv_w4(WConv4 a) {
    int wi = blockIdx.x >> 10;
    int i = (blockIdx.x & 1023) * 256 + threadIdx.x;
    float4 f = a.w[wi][i];
    float s = a.s[wi];
    f.x *= s; f.y *= s; f.z *= s; f.w *= s;
    ushort4 h, l;
    split4(f, h, l);
    a.h[wi][i] = h; a.l[wi][i] = l;
}

// ---------------------------------------------------------------------------
// Shared compute core for the 2-phase GEMMs (round-2 v3, best known good):
// per wave (8 waves = 4M x 2N): 2 fm x 4 fn frags of 16x16x32 MFMA,
// 3-product split-bf16 accumulation (hi*hi + hi*lo + lo*hi).
// LDS frag layout is lane-contiguous 16B per lane (0 read bank conflicts).
// ---------------------------------------------------------------------------
__device__ __forceinline__ void compute_tile(const ushort* Ah, const ushort* Al,
                                             const ushort* Bh, const ushort* Bl,
                                             int wm, int wn, int l,
                                             f32x4 acc[2][4]) {
    bf16x8 bh[4], bl4[4], ah[2], al[2];
#pragma unroll
    for (int fn = 0; fn < 4; ++fn) {
        int fng = wn * 4 + fn;
        bh[fn]  = *(const bf16x8*)&Bh[(fng * 64 + l) * 8];
        bl4[fn] = *(const bf16x8*)&Bl[(fng * 64 + l) * 8];
    }
#pragma unroll
    for (int fm = 0; fm < 2; ++fm) {
        int fmg = wm * 2 + fm;
        ah[fm] = *(const bf16x8*)&Ah[(fmg * 64 + l) * 8];
        al[fm] = *(const bf16x8*)&Al[(fmg * 64 + l) * 8];
    }
    __builtin_amdgcn_s_setprio(1);
#pragma unroll
    for (int fm = 0; fm < 2; ++fm)
#pragma unroll
        for (int fn = 0; fn < 4; ++fn) {
            acc[fm][fn] = __builtin_amdgcn_mfma_f32_16x16x32_bf16(
                ah[fm], bh[fn], acc[fm][fn], 0, 0, 0);
            acc[fm][fn] = __builtin_amdgcn_mfma_f32_16x16x32_bf16(
                ah[fm], bl4[fn], acc[fm][fn], 0, 0, 0);
            acc[fm][fn] = __builtin_amdgcn_mfma_f32_16x16x32_bf16(
                al[fm], bh[fn], acc[fm][fn], 0, 0, 0);
        }
    __builtin_amdgcn_s_setprio(0);
}

// split 8 consecutive fp32 (two float4) -> hi/lo bf16x8, store 16B each
__device__ __forceinline__ void split_write(ushort* Ah, ushort* Al, int aw,
                                            float4 v0, float4 v1) {
    uint4 h4, l4;
    split2(v0.x, v0.y, h4.x, l4.x);
    split2(v0.z, v0.w, h4.y, l4.y);
    split2(v1.x, v1.y, h4.z, l4.z);
    split2(v1.z, v1.w, h4.w, l4.w);
    *(uint4*)&Ah[aw] = h4;
    *(uint4*)&Al[aw] = l4;
}

// ---------------------------------------------------------------------------
// Fused QKV projection GEMM. N = 3072 over fused weights [Wq*s; Wk; Wv].
// ROUND-2 v3 RESTORED VERBATIM (135us, best measured): 128x128 tile, BK=32,
// 512 thr = 8 waves (4M x 2N), double-buffered LDS (64 KB), 2-phase schedule:
// per window issue STAGE(t+1) BEFORE compute(t), then __syncthreads().
// A (fp32) reg-staged one window ahead: global->reg, split hi/lo ONCE per
// element, ds_write pre-split bf16. B via global_load_lds.
// (r4 lesson: per-wave direct-global A frags are 4KB-strided across lanes ->
// uncoalesced, 135->246us. A must go through LDS staging.)
// Outputs: cols [0,1024)->Qhi/Qlo; [1024,2048)->Khi/Klo row-major;
// [2048,3072)->Vthi/Vtlo TRANSPOSED. Row-tiles fully >= slen skip entirely.
// ---------------------------------------------------------------------------
__global__ __launch_bounds__(512, 2) void gemm_qkv(
    const float* __restrict__ Aq, const float* __restrict__ Ak,
    const ushort* __restrict__ Wfh, const ushort* __restrict__ Wfl,
    ushort* __restrict__ Qhi, ushort* __restrict__ Qlo,
    ushort* __restrict__ Khi, ushort* __restrict__ Klo,
    ushort* __restrict__ Vthi, ushort* __restrict__ Vtlo,
    const int* __restrict__ slen)
{
    const int tid = threadIdx.x;
    const int bm = blockIdx.y << 7;
    const int bn = blockIdx.x << 7;        // 0..2944 (fused N = 3072)
    const int grp = bn >> 10;              // 0:Q 1:K 2:V

    const int nk = slen[bm >> 11];
    if ((bm & (Lsz - 1)) >= nk) return;    // skipped tile, never read downstream

    // [buf][region][128*32]; regions: 0=A_hi 1=A_lo 2=B_hi 3=B_lo -> 64 KB
    __shared__ __align__(16) ushort lds[2][4][128 * 32];

    const float* A = (grp == 0) ? Aq : Ak;
    const int w  = tid >> 6;
    const int l  = tid & 63;
    const int wm = w >> 1;                 // 0..3 (M)
    const int wn = w & 1;                  // 0..1 (N)

    // A staging: thread owns row arow, 8 consecutive k at akk (32B/thread,
    // 4 threads per 128B row -> full coalescing). ds_write lands in frag
    // order: slot = (arow>>4)*64 + (akk>>3)*16 + (arow&15)  [bijective in tid].
    const int arow = tid >> 2;
    const int akk  = (tid & 3) << 3;
    const float* ag = A + (size_t)(bm + arow) * GK + akk;
    const int aw = ((((arow >> 4) << 6) + ((akk >> 3) << 4) + (arow & 15)) << 3);

    // B staging: 512 threads x one 16B chunk each of hi and lo per K-tile
    const int brow = ((tid >> 6) << 4) + (tid & 15);
    const int bkk  = ((tid >> 4) & 3) << 3;
    const ushort* bgh = Wfh + (size_t)(bn + brow) * GK + bkk;
    const ushort* bgl = Wfl + (size_t)(bn + brow) * GK + bkk;

    f32x4 acc[2][4];
#pragma unroll
    for (int i = 0; i < 2; ++i)
#pragma unroll
        for (int j = 0; j < 4; ++j) acc[i][j] = (f32x4)0.f;

    // ---- prologue: stage tile0 (A via reg+split, B via gload), prefetch A(1)
    {
        float4 tC0 = *(const float4*)(ag);
        float4 tC1 = *(const float4*)(ag + 4);
        gload16(bgh, &lds[0][2][tid * 8]);
        gload16(bgl, &lds[0][3][tid * 8]);
        split_write(&lds[0][0][0], &lds[0][1][0], aw, tC0, tC1);
    }
    float4 rN0 = *(const float4*)(ag + 32);      // A(1)
    float4 rN1 = *(const float4*)(ag + 36);
    float4 rA0, rA1;                             // A(t+2) in even windows
    __syncthreads();

    // ---- main loop: windows 0..29 (2-unrolled; rN/rA alternate) -----------
    for (int t = 0; t < NT - 2; t += 2) {
        // even window t: stage tile t+1 -> buf1, compute buf0 (tile t)
        rA0 = *(const float4*)(ag + (t + 2) * 32);
        rA1 = *(const float4*)(ag + (t + 2) * 32 + 4);
        gload16(bgh + (t + 1) * 32, &lds[1][2][tid * 8]);
        gload16(bgl + (t + 1) * 32, &lds[1][3][tid * 8]);
        split_write(&lds[1][0][0], &lds[1][1][0], aw, rN0, rN1);  // A(t+1)
        compute_tile(&lds[0][0][0], &lds[0][1][0], &lds[0][2][0], &lds[0][3][0],
                     wm, wn, l, acc);
        __syncthreads();

        // odd window t+1: stage tile t+2 -> buf0, compute buf1 (tile t+1)
        rN0 = *(const float4*)(ag + (t + 3) * 32);               // A(t+3), t+3<=31
        rN1 = *(const float4*)(ag + (t + 3) * 32 + 4);
        gload16(bgh + (t + 2) * 32, &lds[0][2][tid * 8]);
        gload16(bgl + (t + 2) * 32, &lds[0][3][tid * 8]);
        split_write(&lds[0][0][0], &lds[0][1][0], aw, rA0, rA1); // A(t+2)
        compute_tile(&lds[1][0][0], &lds[1][1][0], &lds[1][2][0], &lds[1][3][0],
                     wm, wn, l, acc);
        __syncthreads();
    }

    // ---- window 30: stage tile 31 -> buf1, compute buf0 (tile 30) ---------
    gload16(bgh + (NT - 1) * 32, &lds[1][2][tid * 8]);
    gload16(bgl + (NT - 1) * 32, &lds[1][3][tid * 8]);
    split_write(&lds[1][0][0], &lds[1][1][0], aw, rN0, rN1);      // A(31)
    compute_tile(&lds[0][0][0], &lds[0][1][0], &lds[0][2][0], &lds[0][3][0],
                 wm, wn, l, acc);
    __syncthreads();

    // ---- window 31: compute buf1 (tile 31) --------------------------------
    compute_tile(&lds[1][0][0], &lds[1][1][0], &lds[1][2][0], &lds[1][3][0],
                 wm, wn, l, acc);

    // epilogue: C/D layout row=(l>>4)*4+reg, col=l&15 (m89-verified)
    const int rq = (l >> 4) << 2;
    const int cq = l & 15;
    ushort* OH = (grp == 0) ? Qhi : Khi;   // grp 2 handled below
    ushort* OL = (grp == 0) ? Qlo : Klo;
#pragma unroll
    for (int fm = 0; fm < 2; ++fm) {
        int r0 = bm + wm * 32 + fm * 16 + rq;
#pragma unroll
        for (int fn = 0; fn < 4; ++fn) {
            int cn = (bn & 1023) + wn * 64 + fn * 16 + cq;
            if (grp < 2) {   // Q or K: row-major hi/lo
#pragma unroll
                for (int r = 0; r < 4; ++r) {
                    float f = acc[fm][fn][r];
                    unsigned int u = __float_as_uint(f);
                    float res = f - __uint_as_float(u & 0xffff0000u);
                    OH[(size_t)(r0 + r) * Dsz + cn] = (unsigned short)(u >> 16);
                    OL[(size_t)(r0 + r) * Dsz + cn] =
                        (unsigned short)(__float_as_uint(res) >> 16);
                }
            } else {         // V: transposed hi/lo
                ushort4 h4, l4;
                unsigned short* hp = (unsigned short*)&h4;
                unsigned short* lp = (unsigned short*)&l4;
#pragma unroll
                for (int r = 0; r < 4; ++r) {
                    float f = acc[fm][fn][r];
                    unsigned int u = __float_as_uint(f);
                    float res = f - __uint_as_float(u & 0xffff0000u);
                    hp[r] = (unsigned short)(u >> 16);
                    lp[r] = (unsigned short)(__float_as_uint(res) >> 16);
                }
                *(ushort4*)&Vthi[(size_t)cn * GM + r0] = h4;
                *(ushort4*)&Vtlo[(size_t)cn * GM + r0] = l4;
            }
        }
    }
}

// ---------------------------------------------------------------------------
// O-projection GEMM: out = O @ Wo^T, fp32 result. A pre-split (flash epilogue).
// ROUND-2 v3 RESTORED: 2-phase schedule (STAGE(t+1) -> compute(t) -> sync).
// All four operand tiles via global_load_lds. 512 thr, 8 waves, 64 KB LDS.
// Skipped row-tiles write zeros.
// ---------------------------------------------------------------------------
__global__ __launch_bounds__(512, 2) void gemm_o(
    const ushort* __restrict__ Ahi, const ushort* __restrict__ Alo,
    const ushort* __restrict__ Bhi, const ushort* __restrict__ Blo,
    float* __restrict__ C, const int* __restrict__ slen)
{
    const int tid = threadIdx.x;
    const int bm = blockIdx.y << 7;
    const int bn = blockIdx.x << 7;

    const int nk = slen[bm >> 11];
    if ((bm & (Lsz - 1)) >= nk) {
        int row = tid >> 2;
        int cb  = (tid & 3) << 5;          // 4 col-chunks of 32 floats
        float4 z = make_float4(0.f, 0.f, 0.f, 0.f);
        float4* cp = (float4*)(C + (size_t)(bm + row) * Dsz + bn + cb);
#pragma unroll
        for (int i = 0; i < 8; ++i) cp[i] = z;
        return;
    }

    __shared__ __align__(16) ushort lds[2][4][128 * 32];

    const int w  = tid >> 6;
    const int l  = tid & 63;
    const int wm = w >> 1;
    const int wn = w & 1;

    const int srow = ((tid >> 6) << 4) + (tid & 15);
    const int skk  = ((tid >> 4) & 3) << 3;
    const ushort* agh = Ahi + (size_t)(bm + srow) * GK + skk;
    const ushort* agl = Alo + (size_t)(bm + srow) * GK + skk;
    const ushort* bgh = Bhi + (size_t)(bn + srow) * GK + skk;
    const ushort* bgl = Blo + (size_t)(bn + srow) * GK + skk;

    f32x4 acc[2][4];
#pragma unroll
    for (int i = 0; i < 2; ++i)
#pragma unroll
        for (int j = 0; j < 4; ++j) acc[i][j] = (f32x4)0.f;

    // prologue: stage tile 0 -> buf0, drain, barrier
    gload16(agh, &lds[0][0][tid * 8]);
    gload16(agl, &lds[0][1][tid * 8]);
    gload16(bgh, &lds[0][2][tid * 8]);
    gload16(bgl, &lds[0][3][tid * 8]);
    __syncthreads();

    for (int t = 0; t < NT - 1; ++t) {
        const int p = t & 1;
        const int q = p ^ 1;
        gload16(agh + (t + 1) * 32, &lds[q][0][tid * 8]);
        gload16(agl + (t + 1) * 32, &lds[q][1][tid * 8]);
        gload16(bgh + (t + 1) * 32, &lds[q][2][tid * 8]);
        gload16(bgl + (t + 1) * 32, &lds[q][3][tid * 8]);
        compute_tile(&lds[p][0][0], &lds[p][1][0], &lds[p][2][0], &lds[p][3][0],
                     wm, wn, l, acc);
        __syncthreads();
    }
    {
        const int p = (NT - 1) & 1;
        compute_tile(&lds[p][0][0], &lds[p][1][0], &lds[p][2][0], &lds[p][3][0],
                     wm, wn, l, acc);
    }

    const int rq = (l >> 4) << 2;
    const int cq = l & 15;
#pragma unroll
    for (int fm = 0; fm < 2; ++fm) {
        int r0 = bm + wm * 32 + fm * 16 + rq;
#pragma unroll
        for (int fn = 0; fn < 4; ++fn) {
            int c0 = bn + wn * 64 + fn * 16 + cq;
#pragma unroll
            for (int r = 0; r < 4; ++r)
                C[(size_t)(r0 + r) * Dsz + c0] = acc[fm][fn][r];
        }
    }
}

// ---------------------------------------------------------------------------
// MFMA flash attention, split-bf16, max-free online softmax.
// BQ=128 (512 threads = 8 waves, 16 q-rows each), BK=32, SINGLE-buffered
// LDS (50 KB -> 3 blocks/CU preserved; dbuf regressed earlier).
// v6: T14 ASYNC-STAGE SPLIT. The old loop did gload_lds(t) -> __syncthreads
// (vmcnt(0) drain) -> compute(t): full HBM/L2 latency exposed EVERY tile.
// Now: issue K/V(t+1) global->REG loads (4x dwordx4, +16 VGPR) before
// compute(t); they stay in flight under the whole QK+SM+PV phase. After
// compute: raw lgkmcnt(0)-only barrier (all waves done READING Ks/Vs —
// must NOT drain vmcnt, so no __syncthreads here), then ds_write t+1
// (compiler inserts the vmcnt wait at use; mostly already landed), then
// one __syncthreads (writes visible). Same LDS image bytes, same numerics.
// Masked q-tiles return immediately (gemm_o zero-fills them).
// O written pre-split in-place over Qhi/Qlo.
// ---------------------------------------------------------------------------
__global__ __launch_bounds__(512) void flash_mfma(
    const ushort* __restrict__ Qhi, const ushort* __restrict__ Qlo,
    const ushort* __restrict__ Khi, const ushort* __restrict__ Klo,
    const ushort* __restrict__ Vthi, const ushort* __restrict__ Vtlo,
    const int* __restrict__ slen,
    ushort* __restrict__ Ohi, ushort* __restrict__ Olo)
{
    __shared__ __align__(16) ushort Ks[32 * 256];           // 16 KB
    __shared__ __align__(16) ushort Vs[128 * 64];           // 16 KB
    __shared__ __align__(16) unsigned int Pb[8 * 16 * 36];  // 18 KB

    const int tid = threadIdx.x;
    const int w = tid >> 6, l = tid & 63;
    const int lg = l >> 4, lc = l & 15;
    const int q0 = blockIdx.x << 7;        // 128-row q-tile
    const int h = blockIdx.y, b = blockIdx.z;
    const int nk = slen[b];

    if (q0 >= nk) return;   // gemm_o zero-fills these 128-aligned tiles

    // ---- Q strip -> A-frags (pre-split bf16), once per block ----
    bf16x8 qh[4], ql[4];
    {
        size_t base = (size_t)(b * Lsz + q0 + (w << 4) + lc) * Dsz + h * Dh + lg * 8;
#pragma unroll
        for (int s = 0; s < 4; ++s) {
            qh[s] = *(const bf16x8*)&Qhi[base + s * 32];
            ql[s] = *(const bf16x8*)&Qlo[base + s * 32];
        }
    }

    // ---- staging decode (512 threads, 1024 chunks each of K and Vt) ----
    const ushort* ksrc[2]; int klds[2];
    const ushort* vsrc[2]; int vlds[2];
#pragma unroll
    for (int i = 0; i < 2; ++i) {
        int s = i * 512 + tid;              // K chunk: row j (32ch: 16 hi + 16 lo)
        int j = s >> 5, p = s & 31;
        int lg4 = (p & 15) ^ (j & 15);
        const ushort* base = (p & 16) ? Klo : Khi;
        ksrc[i] = base + (size_t)(b * Lsz + j) * Dsz + h * Dh + lg4 * 8;
        klds[i] = s * 8;
    }
#pragma unroll
    for (int i = 0; i < 2; ++i) {
        int s = i * 512 + tid;              // Vt chunk: row d (8ch: 4 hi + 4 lo)
        int d = s >> 3, p = s & 7;
        int lgc = p ^ (d & 7);
        const ushort* base = (lgc & 4) ? Vtlo : Vthi;
        vsrc[i] = base + (size_t)(h * Dh + d) * (Bsz * Lsz) + b * Lsz + (lgc & 3) * 8;
        vlds[i] = s * 8;
    }

    f32x4 oacc[8];
#pragma unroll
    for (int fd = 0; fd < 8; ++fd) oacc[fd] = (f32x4)0.f;
    float lsum[4] = {0.f, 0.f, 0.f, 0.f};
    const int pbase = w * (16 * 36);

    // ---- prologue: stage tile 0 via global_load_lds, drain, barrier -------
    gload16(ksrc[0], &Ks[klds[0]]);
    gload16(ksrc[1], &Ks[klds[1]]);
    gload16(vsrc[0], &Vs[vlds[0]]);
    gload16(vsrc[1], &Vs[vlds[1]]);
    __syncthreads();

    for (int kb = 0; kb < nk; kb += 32) {
        const bool haveNext = (kb + 32 < nk);   // wave-uniform

        // ---- T14: issue K/V(t+1) global->reg loads; in flight under compute
        uint4 kr0, kr1, vr0, vr1;
        if (haveNext) {
            kr0 = *(const uint4*)(ksrc[0] + (size_t)(kb + 32) * Dsz);
            kr1 = *(const uint4*)(ksrc[1] + (size_t)(kb + 32) * Dsz);
            vr0 = *(const uint4*)(vsrc[0] + (kb + 32));
            vr1 = *(const uint4*)(vsrc[1] + (kb + 32));
        }

        // ---- S = Q K^T (16x32 per wave) ----
        f32x4 sa[2] = {(f32x4)0.f, (f32x4)0.f};
#pragma unroll
        for (int fn = 0; fn < 2; ++fn) {
            int j = fn * 16 + lc;
            int ro = j * 256;
#pragma unroll
            for (int s = 0; s < 4; ++s) {
                int phys = (s * 4 + lg) ^ (j & 15);
                bf16x8 kh = *(const bf16x8*)&Ks[ro + phys * 8];
                bf16x8 kl = *(const bf16x8*)&Ks[ro + 128 + phys * 8];
                sa[fn] = __builtin_amdgcn_mfma_f32_16x16x32_bf16(qh[s], kh, sa[fn], 0, 0, 0);
                sa[fn] = __builtin_amdgcn_mfma_f32_16x16x32_bf16(qh[s], kl, sa[fn], 0, 0, 0);
                sa[fn] = __builtin_amdgcn_mfma_f32_16x16x32_bf16(ql[s], kh, sa[fn], 0, 0, 0);
            }
        }

        // ---- mask tail keys (last tile only; wave-uniform branch) ----
        if (kb + 32 > nk) {
#pragma unroll
            for (int fn = 0; fn < 2; ++fn) {
                bool oob = (kb + fn * 16 + lc) >= nk;
#pragma unroll
                for (int rr = 0; rr < 4; ++rr)
                    sa[fn][rr] = oob ? -1e30f : sa[fn][rr];
            }
        }

        // ---- exp (max-free), accumulate row sums, split+pack P to LDS ----
#pragma unroll
        for (int fn = 0; fn < 2; ++fn)
#pragma unroll
            for (int rr = 0; rr < 4; ++rr) {
                float p = __expf(sa[fn][rr]);
                lsum[rr] += p;
                unsigned int u = __float_as_uint(p);
                float res = p - __uint_as_float(u & 0xffff0000u);
                unsigned int lo16 = __float_as_uint(res) >> 16;
                Pb[pbase + (lg * 4 + rr) * 36 + fn * 16 + lc] =
                    (lo16 << 16) | (u >> 16);
            }

        // ---- P: LDS -> A-frags (per-wave region; no barrier needed) ----
        const unsigned int* pr = &Pb[pbase + lc * 36 + lg * 8];
        uint4 a0 = *(const uint4*)pr;
        uint4 a1 = *(const uint4*)(pr + 4);
        FragU PH, PL;
        PH.u[0] = (a0.x & 0xffffu) | (a0.y << 16);
        PH.u[1] = (a0.z & 0xffffu) | (a0.w << 16);
        PH.u[2] = (a1.x & 0xffffu) | (a1.y << 16);
        PH.u[3] = (a1.z & 0xffffu) | (a1.w << 16);
        PL.u[0] = (a0.x >> 16) | (a0.y & 0xffff0000u);
        PL.u[1] = (a0.z >> 16) | (a0.w & 0xffff0000u);
        PL.u[2] = (a1.x >> 16) | (a1.y & 0xffff0000u);
        PL.u[3] = (a1.z >> 16) | (a1.w & 0xffff0000u);

        // ---- O += P V (16x128 per wave) ----
#pragma unroll
        for (int fd = 0; fd < 8; ++fd) {
            int d = fd * 16 + lc;
            int ro = d * 64;
            int ph = lg ^ (d & 7);
            int pl2 = (4 + lg) ^ (d & 7);
            bf16x8 vh = *(const bf16x8*)&Vs[ro + ph * 8];
            bf16x8 vl = *(const bf16x8*)&Vs[ro + pl2 * 8];
            oacc[fd] = __builtin_amdgcn_mfma_f32_16x16x32_bf16(PH.f, vh, oacc[fd], 0, 0, 0);
            oacc[fd] = __builtin_amdgcn_mfma_f32_16x16x32_bf16(PH.f, vl, oacc[fd], 0, 0, 0);
            oacc[fd] = __builtin_amdgcn_mfma_f32_16x16x32_bf16(PL.f, vh, oacc[fd], 0, 0, 0);
        }

        // ---- write-late: publish K/V(t+1) after everyone finished reading --
        if (haveNext) {
            // raw barrier with lgkm-only drain: my ds ops (frag reads, Pb)
            // done; reg-loads stay in flight (a __syncthreads here would
            // drain vmcnt(0) and kill the overlap).
            asm volatile("s_waitcnt lgkmcnt(0)" ::: "memory");
            __builtin_amdgcn_sched_barrier(0);
            __builtin_amdgcn_s_barrier();
            __builtin_amdgcn_sched_barrier(0);
            *(uint4*)&Ks[klds[0]] = kr0;
            *(uint4*)&Ks[klds[1]] = kr1;
            *(uint4*)&Vs[vlds[0]] = vr0;
            *(uint4*)&Vs[vlds[1]] = vr1;
            __syncthreads();   // writes visible; nothing else outstanding
        }
    }

    // ---- reduce row sums across the 16 lanes of each quad group ----
#pragma unroll
    for (int m = 1; m < 16; m <<= 1)
#pragma unroll
        for (int rr = 0; rr < 4; ++rr)
            lsum[rr] += __shfl_xor(lsum[rr], m, 64);

    // ---- normalize, query-mask, split, store (in-place over Qhi/Qlo) ----
#pragma unroll
    for (int rr = 0; rr < 4; ++rr) {
        int q = q0 + (w << 4) + (lg << 2) + rr;
        bool valid = q < nk;
        float inv = valid ? (1.f / lsum[rr]) : 0.f;
        size_t base = (size_t)(b * Lsz + q) * Dsz + h * Dh + lc;
#pragma unroll
        for (int fd = 0; fd < 8; ++fd) {
            float val = valid ? oacc[fd][rr] * inv : 0.f;
            unsigned int u = __float_as_uint(val);
            float res = val - __uint_as_float(u & 0xffff0000u);
            Ohi[base + fd * 16] = (unsigned short)(u >> 16);
            Olo[base + fd * 16] = (unsigned short)(__float_as_uint(res) >> 16);
        }
    }
}

// ---------------------------------------------------------------------------
// ws: Qhi|Qlo|Khi|Klo|Vthi|Vtlo (6 x MD ushort) + Wfh|Wfl (fused QKV weights,
// 2 x 3WD) + Woh|Wol (2 x WD) = 6 MD + 8 WD ushort = 117.4 MB (validated).
// 4 launches total: conv_w4, gemm_qkv, flash_mfma, gemm_o.
// ---------------------------------------------------------------------------
extern "C" void kernel_launch(void* const* d_in, const int* in_sizes, int n_in,
                              void* d_out, int out_size, void* d_ws, size_t ws_size,
                              hipStream_t stream) {
    (void)in_sizes; (void)n_in; (void)out_size; (void)ws_size;
    const float* queries = (const float*)d_in[0];
    const float* keys    = (const float*)d_in[1];
    const int*   slen    = (const int*)d_in[2];
    const float* Wq      = (const float*)d_in[3];
    const float* Wk      = (const float*)d_in[4];
    const float* Wv      = (const float*)d_in[5];
    const float* Wo      = (const float*)d_in[6];
    float* out = (float*)d_out;

    const size_t MD = (size_t)Bsz * Lsz * Dsz;   // 8388608
    const size_t WD = (size_t)Dsz * Dsz;         // 1048576
    ushort* Qhi  = (ushort*)d_ws;
    ushort* Qlo  = Qhi + MD;
    ushort* Khi  = Qlo + MD;
    ushort* Klo  = Khi + MD;
    ushort* Vthi = Klo + MD;
    ushort* Vtlo = Vthi + MD;
    ushort* Wfh  = Vtlo + MD;      // fused: rows [0,1024)=Wq*s, [1024,2048)=Wk, [2048,3072)=Wv
    ushort* Wfl  = Wfh + 3 * WD;
    ushort* Woh  = Wfl + 3 * WD;
    ushort* Wol  = Woh + WD;

    const float scaleQ = 0.08838834764831845f;   // 1/sqrt(Dh), folded into Wq
    WConv4 wa;
    wa.w[0] = (const float4*)Wq; wa.h[0] = (ushort4*)Wfh;            wa.l[0] = (ushort4*)Wfl;            wa.s[0] = scaleQ;
    wa.w[1] = (const float4*)Wk; wa.h[1] = (ushort4*)(Wfh + WD);     wa.l[1] = (ushort4*)(Wfl + WD);     wa.s[1] = 1.f;
    wa.w[2] = (const float4*)Wv; wa.h[2] = (ushort4*)(Wfh + 2 * WD); wa.l[2] = (ushort4*)(Wfl + 2 * WD); wa.s[2] = 1.f;
    wa.w[3] = (const float4*)Wo; wa.h[3] = (ushort4*)Woh;            wa.l[3] = (ushort4*)Wol;            wa.s[3] = 1.f;
    conv_w4<<<4096, 256, 0, stream>>>(wa);

    // fused Q+K+V projections: N = 3072, grid (24, 64), 512 threads
    gemm_qkv<<<dim3(24, 64), 512, 0, stream>>>(
        queries, keys, Wfh, Wfl, Qhi, Qlo, Khi, Klo, Vthi, Vtlo, slen);

    // flash attention: 128-row q-tiles, 512 threads
    dim3 ga(Lsz / 128, Hn, Bsz);       // (16, 8, 4)
    flash_mfma<<<ga, 512, 0, stream>>>(Qhi, Qlo, Khi, Klo, Vthi, Vtlo, slen,
                                       Qhi, Qlo /* O in-place */);

    // output projection (reads pre-split O; masked tiles -> zeros)
    gemm_o<<<dim3(8, 64), 512, 0, stream>>>(Qhi, Qlo, Woh, Wol, out, slen);
}

// Round 7
// 390.846 us; speedup vs baseline: 1.4018x; 1.1321x over previous
//
#include <hip/hip_runtime.h>
#include <math.h>

// Problem constants (B, L, D, H from the reference)
constexpr int Bsz = 4;
constexpr int Lsz = 2048;
constexpr int Dsz = 1024;
constexpr int Hn  = 8;
constexpr int Dh  = 128;   // Dsz / Hn
constexpr int GM  = Bsz * Lsz;   // 8192
constexpr int GK  = Dsz;         // 1024 (K dim of every projection GEMM)
constexpr int NT  = GK / 32;     // 32 K-tiles of BK=32

typedef __attribute__((ext_vector_type(8))) short bf16x8;
typedef __attribute__((ext_vector_type(4))) float f32x4;

union FragU { unsigned int u[4]; bf16x8 f; };

// async global->LDS, 16B per lane (wave-uniform base + lane*16 dest)
__device__ __forceinline__ void gload16(const void* g, void* l) {
    __builtin_amdgcn_global_load_lds(
        (const __attribute__((address_space(1))) unsigned int*)g,
        (__attribute__((address_space(3))) unsigned int*)l, 16, 0, 0);
}

// split two fp32 into packed bf16 hi-pair / lo-pair (hi=truncate, lo=residual)
__device__ __forceinline__ void split2(float f0, float f1,
                                       unsigned int& hp, unsigned int& lp) {
    unsigned int u0 = __float_as_uint(f0), u1 = __float_as_uint(f1);
    hp = (u0 >> 16) | (u1 & 0xffff0000u);
    float l0 = f0 - __uint_as_float(u0 & 0xffff0000u);
    float l1 = f1 - __uint_as_float(u1 & 0xffff0000u);
    lp = (__float_as_uint(l0) >> 16) | (__float_as_uint(l1) & 0xffff0000u);
}

__device__ __forceinline__ void split4(float4 f, ushort4& h, ushort4& l2) {
    unsigned int ux = __float_as_uint(f.x), uy = __float_as_uint(f.y),
                 uz = __float_as_uint(f.z), uw = __float_as_uint(f.w);
    h.x = (unsigned short)(ux >> 16); h.y = (unsigned short)(uy >> 16);
    h.z = (unsigned short)(uz >> 16); h.w = (unsigned short)(uw >> 16);
    float lx = f.x - __uint_as_float(ux & 0xffff0000u);
    float ly = f.y - __uint_as_float(uy & 0xffff0000u);
    float lz = f.z - __uint_as_float(uz & 0xffff0000u);
    float lw = f.w - __uint_as_float(uw & 0xffff0000u);
    l2.x = (unsigned short)(__float_as_uint(lx) >> 16);
    l2.y = (unsigned short)(__float_as_uint(ly) >> 16);
    l2.z = (unsigned short)(__float_as_uint(lz) >> 16);
    l2.w = (unsigned short)(__float_as_uint(lw) >> 16);
}

struct WConv4 {
    const float4* w[4];
    ushort4* h[4];
    ushort4* l[4];
    float s[4];
};

// 4 weights in one launch: 1024 blocks per weight (WD/4/256 = 1024)
__global__ __launch_bounds__(256) void conv_w4(WConv4 a) {
    int wi = blockIdx.x >> 10;
    int i = (blockIdx.x & 1023) * 256 + threadIdx.x;
    float4 f = a.w[wi][i];
    float s = a.s[wi];
    f.x *= s; f.y *= s; f.z *= s; f.w *= s;
    ushort4 h, l;
    split4(f, h, l);
    a.h[wi][i] = h; a.l[wi][i] = l;
}

// ---------------------------------------------------------------------------
// Shared compute core for the 2-phase GEMMs (round-2 v3, best known good):
// per wave (8 waves = 4M x 2N): 2 fm x 4 fn frags of 16x16x32 MFMA,
// 3-product split-bf16 accumulation (hi*hi + hi*lo + lo*hi).
// LDS frag layout is lane-contiguous 16B per lane (0 read bank conflicts).
// ---------------------------------------------------------------------------
__device__ __forceinline__ void compute_tile(const ushort* Ah, const ushort* Al,
                                             const ushort* Bh, const ushort* Bl,
                                             int wm, int wn, int l,
                                             f32x4 acc[2][4]) {
    bf16x8 bh[4], bl4[4], ah[2], al[2];
#pragma unroll
    for (int fn = 0; fn < 4; ++fn) {
        int fng = wn * 4 + fn;
        bh[fn]  = *(const bf16x8*)&Bh[(fng * 64 + l) * 8];
        bl4[fn] = *(const bf16x8*)&Bl[(fng * 64 + l) * 8];
    }
#pragma unroll
    for (int fm = 0; fm < 2; ++fm) {
        int fmg = wm * 2 + fm;
        ah[fm] = *(const bf16x8*)&Ah[(fmg * 64 + l) * 8];
        al[fm] = *(const bf16x8*)&Al[(fmg * 64 + l) * 8];
    }
    __builtin_amdgcn_s_setprio(1);
#pragma unroll
    for (int fm = 0; fm < 2; ++fm)
#pragma unroll
        for (int fn = 0; fn < 4; ++fn) {
            acc[fm][fn] = __builtin_amdgcn_mfma_f32_16x16x32_bf16(
                ah[fm], bh[fn], acc[fm][fn], 0, 0, 0);
            acc[fm][fn] = __builtin_amdgcn_mfma_f32_16x16x32_bf16(
                ah[fm], bl4[fn], acc[fm][fn], 0, 0, 0);
            acc[fm][fn] = __builtin_amdgcn_mfma_f32_16x16x32_bf16(
                al[fm], bh[fn], acc[fm][fn], 0, 0, 0);
        }
    __builtin_amdgcn_s_setprio(0);
}

// split 8 consecutive fp32 (two float4) -> hi/lo bf16x8, store 16B each
__device__ __forceinline__ void split_write(ushort* Ah, ushort* Al, int aw,
                                            float4 v0, float4 v1) {
    uint4 h4, l4;
    split2(v0.x, v0.y, h4.x, l4.x);
    split2(v0.z, v0.w, h4.y, l4.y);
    split2(v1.x, v1.y, h4.z, l4.z);
    split2(v1.z, v1.w, h4.w, l4.w);
    *(uint4*)&Ah[aw] = h4;
    *(uint4*)&Al[aw] = l4;
}

// ---------------------------------------------------------------------------
// Fused QKV projection GEMM. N = 3072 over fused weights [Wq*s; Wk; Wv].
// ROUND-2 v3 (135us, best measured): 128x128 tile, BK=32, 512 thr = 8 waves
// (4M x 2N), double-buffered LDS (64 KB), 2-phase: STAGE(t+1) before
// compute(t), then __syncthreads(). A (fp32) reg-staged one window ahead,
// split hi/lo once per element at staging. B via global_load_lds.
// (r4 lesson: direct-global A frags are 4KB-strided -> uncoalesced, 246us.)
// Outputs: cols [0,1024)->Qhi/Qlo; [1024,2048)->Khi/Klo row-major;
// [2048,3072)->Vthi/Vtlo TRANSPOSED. Row-tiles fully >= slen skip entirely.
// ---------------------------------------------------------------------------
__global__ __launch_bounds__(512, 2) void gemm_qkv(
    const float* __restrict__ Aq, const float* __restrict__ Ak,
    const ushort* __restrict__ Wfh, const ushort* __restrict__ Wfl,
    ushort* __restrict__ Qhi, ushort* __restrict__ Qlo,
    ushort* __restrict__ Khi, ushort* __restrict__ Klo,
    ushort* __restrict__ Vthi, ushort* __restrict__ Vtlo,
    const int* __restrict__ slen)
{
    const int tid = threadIdx.x;
    const int bm = blockIdx.y << 7;
    const int bn = blockIdx.x << 7;        // 0..2944 (fused N = 3072)
    const int grp = bn >> 10;              // 0:Q 1:K 2:V

    const int nk = slen[bm >> 11];
    if ((bm & (Lsz - 1)) >= nk) return;    // skipped tile, never read downstream

    // [buf][region][128*32]; regions: 0=A_hi 1=A_lo 2=B_hi 3=B_lo -> 64 KB
    __shared__ __align__(16) ushort lds[2][4][128 * 32];

    const float* A = (grp == 0) ? Aq : Ak;
    const int w  = tid >> 6;
    const int l  = tid & 63;
    const int wm = w >> 1;                 // 0..3 (M)
    const int wn = w & 1;                  // 0..1 (N)

    // A staging: thread owns row arow, 8 consecutive k at akk (32B/thread,
    // 4 threads per 128B row -> full coalescing). ds_write lands in frag
    // order: slot = (arow>>4)*64 + (akk>>3)*16 + (arow&15)  [bijective in tid].
    const int arow = tid >> 2;
    const int akk  = (tid & 3) << 3;
    const float* ag = A + (size_t)(bm + arow) * GK + akk;
    const int aw = ((((arow >> 4) << 6) + ((akk >> 3) << 4) + (arow & 15)) << 3);

    // B staging: 512 threads x one 16B chunk each of hi and lo per K-tile
    const int brow = ((tid >> 6) << 4) + (tid & 15);
    const int bkk  = ((tid >> 4) & 3) << 3;
    const ushort* bgh = Wfh + (size_t)(bn + brow) * GK + bkk;
    const ushort* bgl = Wfl + (size_t)(bn + brow) * GK + bkk;

    f32x4 acc[2][4];
#pragma unroll
    for (int i = 0; i < 2; ++i)
#pragma unroll
        for (int j = 0; j < 4; ++j) acc[i][j] = (f32x4)0.f;

    // ---- prologue: stage tile0 (A via reg+split, B via gload), prefetch A(1)
    {
        float4 tC0 = *(const float4*)(ag);
        float4 tC1 = *(const float4*)(ag + 4);
        gload16(bgh, &lds[0][2][tid * 8]);
        gload16(bgl, &lds[0][3][tid * 8]);
        split_write(&lds[0][0][0], &lds[0][1][0], aw, tC0, tC1);
    }
    float4 rN0 = *(const float4*)(ag + 32);      // A(1)
    float4 rN1 = *(const float4*)(ag + 36);
    float4 rA0, rA1;                             // A(t+2) in even windows
    __syncthreads();

    // ---- main loop: windows 0..29 (2-unrolled; rN/rA alternate) -----------
    for (int t = 0; t < NT - 2; t += 2) {
        // even window t: stage tile t+1 -> buf1, compute buf0 (tile t)
        rA0 = *(const float4*)(ag + (t + 2) * 32);
        rA1 = *(const float4*)(ag + (t + 2) * 32 + 4);
        gload16(bgh + (t + 1) * 32, &lds[1][2][tid * 8]);
        gload16(bgl + (t + 1) * 32, &lds[1][3][tid * 8]);
        split_write(&lds[1][0][0], &lds[1][1][0], aw, rN0, rN1);  // A(t+1)
        compute_tile(&lds[0][0][0], &lds[0][1][0], &lds[0][2][0], &lds[0][3][0],
                     wm, wn, l, acc);
        __syncthreads();

        // odd window t+1: stage tile t+2 -> buf0, compute buf1 (tile t+1)
        rN0 = *(const float4*)(ag + (t + 3) * 32);               // A(t+3), t+3<=31
        rN1 = *(const float4*)(ag + (t + 3) * 32 + 4);
        gload16(bgh + (t + 2) * 32, &lds[0][2][tid * 8]);
        gload16(bgl + (t + 2) * 32, &lds[0][3][tid * 8]);
        split_write(&lds[0][0][0], &lds[0][1][0], aw, rA0, rA1); // A(t+2)
        compute_tile(&lds[1][0][0], &lds[1][1][0], &lds[1][2][0], &lds[1][3][0],
                     wm, wn, l, acc);
        __syncthreads();
    }

    // ---- window 30: stage tile 31 -> buf1, compute buf0 (tile 30) ---------
    gload16(bgh + (NT - 1) * 32, &lds[1][2][tid * 8]);
    gload16(bgl + (NT - 1) * 32, &lds[1][3][tid * 8]);
    split_write(&lds[1][0][0], &lds[1][1][0], aw, rN0, rN1);      // A(31)
    compute_tile(&lds[0][0][0], &lds[0][1][0], &lds[0][2][0], &lds[0][3][0],
                 wm, wn, l, acc);
    __syncthreads();

    // ---- window 31: compute buf1 (tile 31) --------------------------------
    compute_tile(&lds[1][0][0], &lds[1][1][0], &lds[1][2][0], &lds[1][3][0],
                 wm, wn, l, acc);

    // epilogue: C/D layout row=(l>>4)*4+reg, col=l&15 (m89-verified)
    const int rq = (l >> 4) << 2;
    const int cq = l & 15;
    ushort* OH = (grp == 0) ? Qhi : Khi;   // grp 2 handled below
    ushort* OL = (grp == 0) ? Qlo : Klo;
#pragma unroll
    for (int fm = 0; fm < 2; ++fm) {
        int r0 = bm + wm * 32 + fm * 16 + rq;
#pragma unroll
        for (int fn = 0; fn < 4; ++fn) {
            int cn = (bn & 1023) + wn * 64 + fn * 16 + cq;
            if (grp < 2) {   // Q or K: row-major hi/lo
#pragma unroll
                for (int r = 0; r < 4; ++r) {
                    float f = acc[fm][fn][r];
                    unsigned int u = __float_as_uint(f);
                    float res = f - __uint_as_float(u & 0xffff0000u);
                    OH[(size_t)(r0 + r) * Dsz + cn] = (unsigned short)(u >> 16);
                    OL[(size_t)(r0 + r) * Dsz + cn] =
                        (unsigned short)(__float_as_uint(res) >> 16);
                }
            } else {         // V: transposed hi/lo
                ushort4 h4, l4;
                unsigned short* hp = (unsigned short*)&h4;
                unsigned short* lp = (unsigned short*)&l4;
#pragma unroll
                for (int r = 0; r < 4; ++r) {
                    float f = acc[fm][fn][r];
                    unsigned int u = __float_as_uint(f);
                    float res = f - __uint_as_float(u & 0xffff0000u);
                    hp[r] = (unsigned short)(u >> 16);
                    lp[r] = (unsigned short)(__float_as_uint(res) >> 16);
                }
                *(ushort4*)&Vthi[(size_t)cn * GM + r0] = h4;
                *(ushort4*)&Vtlo[(size_t)cn * GM + r0] = l4;
            }
        }
    }
}

// ---------------------------------------------------------------------------
// O-projection GEMM: out = O @ Wo^T, fp32 result. A pre-split (flash epilogue).
// ROUND-2 v3: 2-phase schedule (STAGE(t+1) -> compute(t) -> sync).
// All four operand tiles via global_load_lds. 512 thr, 8 waves, 64 KB LDS.
// Skipped row-tiles write zeros.
// ---------------------------------------------------------------------------
__global__ __launch_bounds__(512, 2) void gemm_o(
    const ushort* __restrict__ Ahi, const ushort* __restrict__ Alo,
    const ushort* __restrict__ Bhi, const ushort* __restrict__ Blo,
    float* __restrict__ C, const int* __restrict__ slen)
{
    const int tid = threadIdx.x;
    const int bm = blockIdx.y << 7;
    const int bn = blockIdx.x << 7;

    const int nk = slen[bm >> 11];
    if ((bm & (Lsz - 1)) >= nk) {
        int row = tid >> 2;
        int cb  = (tid & 3) << 5;          // 4 col-chunks of 32 floats
        float4 z = make_float4(0.f, 0.f, 0.f, 0.f);
        float4* cp = (float4*)(C + (size_t)(bm + row) * Dsz + bn + cb);
#pragma unroll
        for (int i = 0; i < 8; ++i) cp[i] = z;
        return;
    }

    __shared__ __align__(16) ushort lds[2][4][128 * 32];

    const int w  = tid >> 6;
    const int l  = tid & 63;
    const int wm = w >> 1;
    const int wn = w & 1;

    const int srow = ((tid >> 6) << 4) + (tid & 15);
    const int skk  = ((tid >> 4) & 3) << 3;
    const ushort* agh = Ahi + (size_t)(bm + srow) * GK + skk;
    const ushort* agl = Alo + (size_t)(bm + srow) * GK + skk;
    const ushort* bgh = Bhi + (size_t)(bn + srow) * GK + skk;
    const ushort* bgl = Blo + (size_t)(bn + srow) * GK + skk;

    f32x4 acc[2][4];
#pragma unroll
    for (int i = 0; i < 2; ++i)
#pragma unroll
        for (int j = 0; j < 4; ++j) acc[i][j] = (f32x4)0.f;

    // prologue: stage tile 0 -> buf0, drain, barrier
    gload16(agh, &lds[0][0][tid * 8]);
    gload16(agl, &lds[0][1][tid * 8]);
    gload16(bgh, &lds[0][2][tid * 8]);
    gload16(bgl, &lds[0][3][tid * 8]);
    __syncthreads();

    for (int t = 0; t < NT - 1; ++t) {
        const int p = t & 1;
        const int q = p ^ 1;
        gload16(agh + (t + 1) * 32, &lds[q][0][tid * 8]);
        gload16(agl + (t + 1) * 32, &lds[q][1][tid * 8]);
        gload16(bgh + (t + 1) * 32, &lds[q][2][tid * 8]);
        gload16(bgl + (t + 1) * 32, &lds[q][3][tid * 8]);
        compute_tile(&lds[p][0][0], &lds[p][1][0], &lds[p][2][0], &lds[p][3][0],
                     wm, wn, l, acc);
        __syncthreads();
    }
    {
        const int p = (NT - 1) & 1;
        compute_tile(&lds[p][0][0], &lds[p][1][0], &lds[p][2][0], &lds[p][3][0],
                     wm, wn, l, acc);
    }

    const int rq = (l >> 4) << 2;
    const int cq = l & 15;
#pragma unroll
    for (int fm = 0; fm < 2; ++fm) {
        int r0 = bm + wm * 32 + fm * 16 + rq;
#pragma unroll
        for (int fn = 0; fn < 4; ++fn) {
            int c0 = bn + wn * 64 + fn * 16 + cq;
#pragma unroll
            for (int r = 0; r < 4; ++r)
                C[(size_t)(r0 + r) * Dsz + c0] = acc[fm][fn][r];
        }
    }
}

// ---------------------------------------------------------------------------
// MFMA flash attention, split-bf16, max-free online softmax.
// v7: BQ=64 (256 threads = 4 waves, 16 q-rows each), BK=32, SINGLE-buffered,
// round-2 staging restored (gload_lds -> __syncthreads; r5's T14 reg-staging
// regressed 40us: added a serialized vmcnt->ds_write->barrier chain with no
// TLP to hide it). WHY BQ=64: r5 counters showed Occupancy 11% — only ~250
// working blocks at BQ=128 for 256 CUs = 1 block/CU, everything latency-
// serialized. BQ=64 doubles the grid to ~500 working blocks = 2 independent
// blocks/CU; one block's staging drain overlaps the other's MFMA (m114
// inter-block overlap). Per-wave work per tile is unchanged. LDS 41 KB.
// SKIP LOGIC: gemm_o zero-skips at 128-row granularity, so a 64-tile whose
// parent 128-tile is live but whose own q0 >= nk must WRITE ZEROS (not
// return) — otherwise gemm_o reads stale Q rows.
// O written pre-split in-place over Qhi/Qlo.
// ---------------------------------------------------------------------------
__global__ __launch_bounds__(256) void flash_mfma(
    const ushort* __restrict__ Qhi, const ushort* __restrict__ Qlo,
    const ushort* __restrict__ Khi, const ushort* __restrict__ Klo,
    const ushort* __restrict__ Vthi, const ushort* __restrict__ Vtlo,
    const int* __restrict__ slen,
    ushort* __restrict__ Ohi, ushort* __restrict__ Olo)
{
    __shared__ __align__(16) ushort Ks[32 * 256];           // 16 KB
    __shared__ __align__(16) ushort Vs[128 * 64];           // 16 KB
    __shared__ __align__(16) unsigned int Pb[4 * 16 * 36];  // 9 KB

    const int tid = threadIdx.x;
    const int w = tid >> 6, l = tid & 63;
    const int lg = l >> 4, lc = l & 15;
    const int q0 = blockIdx.x << 6;        // 64-row q-tile
    const int h = blockIdx.y, b = blockIdx.z;
    const int nk = slen[b];

    if ((q0 & ~127) >= nk) return;         // parent 128-tile skipped by gemm_o

    if (q0 >= nk) {
        // parent tile live but this half fully masked: write zeros so gemm_o
        // never reads stale Q rows.
#pragma unroll
        for (int rr = 0; rr < 4; ++rr) {
            int q = q0 + (w << 4) + (lg << 2) + rr;
            size_t base = (size_t)(b * Lsz + q) * Dsz + h * Dh + lc;
#pragma unroll
            for (int fd = 0; fd < 8; ++fd) {
                Ohi[base + fd * 16] = 0;
                Olo[base + fd * 16] = 0;
            }
        }
        return;
    }

    // ---- Q strip -> A-frags (pre-split bf16), once per block ----
    bf16x8 qh[4], ql[4];
    {
        size_t base = (size_t)(b * Lsz + q0 + (w << 4) + lc) * Dsz + h * Dh + lg * 8;
#pragma unroll
        for (int s = 0; s < 4; ++s) {
            qh[s] = *(const bf16x8*)&Qhi[base + s * 32];
            ql[s] = *(const bf16x8*)&Qlo[base + s * 32];
        }
    }

    // ---- staging decode (256 threads, 1024 chunks each of K and Vt) ----
    const ushort* ksrc[4]; int klds[4];
    const ushort* vsrc[4]; int vlds[4];
#pragma unroll
    for (int i = 0; i < 4; ++i) {
        int s = i * 256 + tid;              // K chunk: row j (32ch: 16 hi + 16 lo)
        int j = s >> 5, p = s & 31;
        int lg4 = (p & 15) ^ (j & 15);
        const ushort* base = (p & 16) ? Klo : Khi;
        ksrc[i] = base + (size_t)(b * Lsz + j) * Dsz + h * Dh + lg4 * 8;
        klds[i] = s * 8;
    }
#pragma unroll
    for (int i = 0; i < 4; ++i) {
        int s = i * 256 + tid;              // Vt chunk: row d (8ch: 4 hi + 4 lo)
        int d = s >> 3, p = s & 7;
        int lgc = p ^ (d & 7);
        const ushort* base = (lgc & 4) ? Vtlo : Vthi;
        vsrc[i] = base + (size_t)(h * Dh + d) * (Bsz * Lsz) + b * Lsz + (lgc & 3) * 8;
        vlds[i] = s * 8;
    }

    f32x4 oacc[8];
#pragma unroll
    for (int fd = 0; fd < 8; ++fd) oacc[fd] = (f32x4)0.f;
    float lsum[4] = {0.f, 0.f, 0.f, 0.f};
    const int pbase = w * (16 * 36);

    for (int kb = 0; kb < nk; kb += 32) {
        // ---- stage K + V^T tiles ----
#pragma unroll
        for (int i = 0; i < 4; ++i) gload16(ksrc[i] + (size_t)kb * Dsz, &Ks[klds[i]]);
#pragma unroll
        for (int i = 0; i < 4; ++i) gload16(vsrc[i] + kb, &Vs[vlds[i]]);
        __syncthreads();

        // ---- S = Q K^T (16x32 per wave) ----
        f32x4 sa[2] = {(f32x4)0.f, (f32x4)0.f};
#pragma unroll
        for (int fn = 0; fn < 2; ++fn) {
            int j = fn * 16 + lc;
            int ro = j * 256;
#pragma unroll
            for (int s = 0; s < 4; ++s) {
                int phys = (s * 4 + lg) ^ (j & 15);
                bf16x8 kh = *(const bf16x8*)&Ks[ro + phys * 8];
                bf16x8 kl = *(const bf16x8*)&Ks[ro + 128 + phys * 8];
                sa[fn] = __builtin_amdgcn_mfma_f32_16x16x32_bf16(qh[s], kh, sa[fn], 0, 0, 0);
                sa[fn] = __builtin_amdgcn_mfma_f32_16x16x32_bf16(qh[s], kl, sa[fn], 0, 0, 0);
                sa[fn] = __builtin_amdgcn_mfma_f32_16x16x32_bf16(ql[s], kh, sa[fn], 0, 0, 0);
            }
        }

        // ---- mask tail keys (last tile only; wave-uniform branch) ----
        if (kb + 32 > nk) {
#pragma unroll
            for (int fn = 0; fn < 2; ++fn) {
                bool oob = (kb + fn * 16 + lc) >= nk;
#pragma unroll
                for (int rr = 0; rr < 4; ++rr)
                    sa[fn][rr] = oob ? -1e30f : sa[fn][rr];
            }
        }

        // ---- exp (max-free), accumulate row sums, split+pack P to LDS ----
#pragma unroll
        for (int fn = 0; fn < 2; ++fn)
#pragma unroll
            for (int rr = 0; rr < 4; ++rr) {
                float p = __expf(sa[fn][rr]);
                lsum[rr] += p;
                unsigned int u = __float_as_uint(p);
                float res = p - __uint_as_float(u & 0xffff0000u);
                unsigned int lo16 = __float_as_uint(res) >> 16;
                Pb[pbase + (lg * 4 + rr) * 36 + fn * 16 + lc] =
                    (lo16 << 16) | (u >> 16);
            }

        // ---- P: LDS -> A-frags (per-wave region; no barrier needed) ----
        const unsigned int* pr = &Pb[pbase + lc * 36 + lg * 8];
        uint4 a0 = *(const uint4*)pr;
        uint4 a1 = *(const uint4*)(pr + 4);
        FragU PH, PL;
        PH.u[0] = (a0.x & 0xffffu) | (a0.y << 16);
        PH.u[1] = (a0.z & 0xffffu) | (a0.w << 16);
        PH.u[2] = (a1.x & 0xffffu) | (a1.y << 16);
        PH.u[3] = (a1.z & 0xffffu) | (a1.w << 16);
        PL.u[0] = (a0.x >> 16) | (a0.y & 0xffff0000u);
        PL.u[1] = (a0.z >> 16) | (a0.w & 0xffff0000u);
        PL.u[2] = (a1.x >> 16) | (a1.y & 0xffff0000u);
        PL.u[3] = (a1.z >> 16) | (a1.w & 0xffff0000u);

        // ---- O += P V (16x128 per wave) ----
#pragma unroll
        for (int fd = 0; fd < 8; ++fd) {
            int d = fd * 16 + lc;
            int ro = d * 64;
            int ph = lg ^ (d & 7);
            int pl2 = (4 + lg) ^ (d & 7);
            bf16x8 vh = *(const bf16x8*)&Vs[ro + ph * 8];
            bf16x8 vl = *(const bf16x8*)&Vs[ro + pl2 * 8];
            oacc[fd] = __builtin_amdgcn_mfma_f32_16x16x32_bf16(PH.f, vh, oacc[fd], 0, 0, 0);
            oacc[fd] = __builtin_amdgcn_mfma_f32_16x16x32_bf16(PH.f, vl, oacc[fd], 0, 0, 0);
            oacc[fd] = __builtin_amdgcn_mfma_f32_16x16x32_bf16(PL.f, vh, oacc[fd], 0, 0, 0);
        }
        __syncthreads();   // protect Ks/Vs before next stage
    }

    // ---- reduce row sums across the 16 lanes of each quad group ----
#pragma unroll
    for (int m = 1; m < 16; m <<= 1)
#pragma unroll
        for (int rr = 0; rr < 4; ++rr)
            lsum[rr] += __shfl_xor(lsum[rr], m, 64);

    // ---- normalize, query-mask, split, store (in-place over Qhi/Qlo) ----
#pragma unroll
    for (int rr = 0; rr < 4; ++rr) {
        int q = q0 + (w << 4) + (lg << 2) + rr;
        bool valid = q < nk;
        float inv = valid ? (1.f / lsum[rr]) : 0.f;
        size_t base = (size_t)(b * Lsz + q) * Dsz + h * Dh + lc;
#pragma unroll
        for (int fd = 0; fd < 8; ++fd) {
            float val = valid ? oacc[fd][rr] * inv : 0.f;
            unsigned int u = __float_as_uint(val);
            float res = val - __uint_as_float(u & 0xffff0000u);
            Ohi[base + fd * 16] = (unsigned short)(u >> 16);
            Olo[base + fd * 16] = (unsigned short)(__float_as_uint(res) >> 16);
        }
    }
}

// ---------------------------------------------------------------------------
// ws: Qhi|Qlo|Khi|Klo|Vthi|Vtlo (6 x MD ushort) + Wfh|Wfl (fused QKV weights,
// 2 x 3WD) + Woh|Wol (2 x WD) = 6 MD + 8 WD ushort = 117.4 MB (validated).
// 4 launches total: conv_w4, gemm_qkv, flash_mfma, gemm_o.
// ---------------------------------------------------------------------------
extern "C" void kernel_launch(void* const* d_in, const int* in_sizes, int n_in,
                              void* d_out, int out_size, void* d_ws, size_t ws_size,
                              hipStream_t stream) {
    (void)in_sizes; (void)n_in; (void)out_size; (void)ws_size;
    const float* queries = (const float*)d_in[0];
    const float* keys    = (const float*)d_in[1];
    const int*   slen    = (const int*)d_in[2];
    const float* Wq      = (const float*)d_in[3];
    const float* Wk      = (const float*)d_in[4];
    const float* Wv      = (const float*)d_in[5];
    const float* Wo      = (const float*)d_in[6];
    float* out = (float*)d_out;

    const size_t MD = (size_t)Bsz * Lsz * Dsz;   // 8388608
    const size_t WD = (size_t)Dsz * Dsz;         // 1048576
    ushort* Qhi  = (ushort*)d_ws;
    ushort* Qlo  = Qhi + MD;
    ushort* Khi  = Qlo + MD;
    ushort* Klo  = Khi + MD;
    ushort* Vthi = Klo + MD;
    ushort* Vtlo = Vthi + MD;
    ushort* Wfh  = Vtlo + MD;      // fused: rows [0,1024)=Wq*s, [1024,2048)=Wk, [2048,3072)=Wv
    ushort* Wfl  = Wfh + 3 * WD;
    ushort* Woh  = Wfl + 3 * WD;
    ushort* Wol  = Woh + WD;

    const float scaleQ = 0.08838834764831845f;   // 1/sqrt(Dh), folded into Wq
    WConv4 wa;
    wa.w[0] = (const float4*)Wq; wa.h[0] = (ushort4*)Wfh;            wa.l[0] = (ushort4*)Wfl;            wa.s[0] = scaleQ;
    wa.w[1] = (const float4*)Wk; wa.h[1] = (ushort4*)(Wfh + WD);     wa.l[1] = (ushort4*)(Wfl + WD);     wa.s[1] = 1.f;
    wa.w[2] = (const float4*)Wv; wa.h[2] = (ushort4*)(Wfh + 2 * WD); wa.l[2] = (ushort4*)(Wfl + 2 * WD); wa.s[2] = 1.f;
    wa.w[3] = (const float4*)Wo; wa.h[3] = (ushort4*)Woh;            wa.l[3] = (ushort4*)Wol;            wa.s[3] = 1.f;
    conv_w4<<<4096, 256, 0, stream>>>(wa);

    // fused Q+K+V projections: N = 3072, grid (24, 64), 512 threads
    gemm_qkv<<<dim3(24, 64), 512, 0, stream>>>(
        queries, keys, Wfh, Wfl, Qhi, Qlo, Khi, Klo, Vthi, Vtlo, slen);

    // flash attention: 64-row q-tiles, 256 threads (4 waves)
    dim3 ga(Lsz / 64, Hn, Bsz);        // (32, 8, 4)
    flash_mfma<<<ga, 256, 0, stream>>>(Qhi, Qlo, Khi, Klo, Vthi, Vtlo, slen,
                                       Qhi, Qlo /* O in-place */);

    // output projection (reads pre-split O; masked tiles -> zeros)
    gemm_o<<<dim3(8, 64), 512, 0, stream>>>(Qhi, Qlo, Woh, Wol, out, slen);
}